// Round 3
// baseline (5349.158 us; speedup 1.0000x reference)
//
#include <hip/hip_runtime.h>
#include <hip/hip_bf16.h>

typedef unsigned short u16;
typedef unsigned int u32;
typedef __attribute__((ext_vector_type(4))) float f32x4;
typedef __attribute__((ext_vector_type(8))) short s16x8;

#define OREC 8388608
#define OH 16777216
#define OLOSS 17301504

__device__ __forceinline__ float bf2f(u16 u) {
    union { u32 i; float f; } v; v.i = ((u32)u) << 16; return v.f;
}
__device__ __forceinline__ u16 f2bf(float f) {
    union { float f; u32 i; } v; v.f = f;
    u32 i = v.i;
    u32 r = i + 0x7FFFu + ((i >> 16) & 1u);
    return (u16)(r >> 16);
}
__device__ __forceinline__ float ldin(const void* p, int i, int bf) {
    return bf ? bf2f(((const u16*)p)[i]) : ((const float*)p)[i];
}
__device__ __forceinline__ void stout(void* p, int i, float v, int bf) {
    if (bf) ((u16*)p)[i] = f2bf(v); else ((float*)p)[i] = v;
}

#define ZACC(A) do { \
    _Pragma("unroll") for (int zi = 0; zi < 2; ++zi) \
    _Pragma("unroll") for (int zj = 0; zj < 2; ++zj) \
    _Pragma("unroll") for (int zq = 0; zq < 4; ++zq) A[zi][zj][zq] = 0.f; \
} while (0)

// ---- legacy 64x64 GEMM core (used by one-time gammaH/beta precompute) ----
__device__ __forceinline__ void stage_tile(const u16* __restrict__ src, int ld, int row0, int k0,
                                           u16* lds) {
    int t = threadIdx.x;
    int row = t >> 2, seg = t & 3;
    const u16* g = src + (size_t)(row0 + row) * ld + k0 + (seg << 3);
    uint4 v = *(const uint4*)g;
    *(uint4*)&lds[(row << 5) + ((seg ^ (row & 3)) << 3)] = v;
}

__device__ __forceinline__ void gemm_loop(const u16* __restrict__ A, int lda,
                                          const u16* __restrict__ W, int ldw,
                                          int K, int m0, int n0,
                                          u16* lA, u16* lB, f32x4 acc[2][2]) {
    int lane = threadIdx.x & 63;
    int wid = threadIdx.x >> 6;
    int wr = wid >> 1, wc = wid & 1;
    int lrow = lane & 15, lseg = lane >> 4;
    int sw = (lseg ^ (lrow & 3)) << 3;
    for (int k0 = 0; k0 < K; k0 += 32) {
        __syncthreads();
        stage_tile(A, lda, m0, k0, lA);
        stage_tile(W, ldw, n0, k0, lB);
        __syncthreads();
        s16x8 af[2], bg[2];
#pragma unroll
        for (int i = 0; i < 2; i++) {
            int r = (wr << 5) + (i << 4) + lrow;
            af[i] = *(const s16x8*)&lA[(r << 5) + sw];
            int c = (wc << 5) + (i << 4) + lrow;
            bg[i] = *(const s16x8*)&lB[(c << 5) + sw];
        }
#pragma unroll
        for (int i = 0; i < 2; i++)
#pragma unroll
            for (int j = 0; j < 2; j++)
                acc[i][j] = __builtin_amdgcn_mfma_f32_16x16x32_bf16(af[i], bg[j], acc[i][j], 0, 0, 0);
    }
}

// ---- prologue kernels ----
__global__ void k_zero(int* flag, float* lossN, float* lossD) {
    if (threadIdx.x == 0) *flag = 0;
    if (threadIdx.x < 64) { lossN[threadIdx.x] = 0.f; lossD[threadIdx.x] = 0.f; }
}

__global__ void k_detect(const u32* __restrict__ w, int* flag) {
    int gid = blockIdx.x * 256 + threadIdx.x;
    int found = 0;
    for (int i = gid; i < (1 << 20); i += 65536) {
        if ((w[i] & 0xFFFFu) == 0x3F80u) found = 1;
    }
    if (found) atomicOr(flag, 1);
}

__global__ void k_cvt_bf(const void* __restrict__ src, u16* __restrict__ dst, int n,
                         const int* __restrict__ flagp) {
    int bf = *flagp;
    for (int i = blockIdx.x * 256 + threadIdx.x; i < n; i += gridDim.x * 256)
        dst[i] = bf ? ((const u16*)src)[i] : f2bf(((const float*)src)[i]);
}

// merged bias conversion: layout [0,1024)=bdh [1024,1280)=bdx [1280,1536)=bh
// [1536,1792)=bfr [1792,2048)=bwc [2048,5120)=bih [5120,8192)=bhh
__global__ void k_cvt_biases(const void* __restrict__ bdh, const void* __restrict__ bdx,
                             const void* __restrict__ bh, const void* __restrict__ bfr,
                             const void* __restrict__ bwc, const void* __restrict__ bih,
                             const void* __restrict__ bhh, float* __restrict__ dst,
                             const int* __restrict__ flagp) {
    int bf = *flagp;
    int i = blockIdx.x * 256 + threadIdx.x;  // 8192
    const void* src; int off;
    if (i < 1024) { src = bdh; off = 0; }
    else if (i < 1280) { src = bdx; off = 1024; }
    else if (i < 1536) { src = bh; off = 1280; }
    else if (i < 1792) { src = bfr; off = 1536; }
    else if (i < 2048) { src = bwc; off = 1792; }
    else if (i < 5120) { src = bih; off = 2048; }
    else { src = bhh; off = 5120; }
    dst[i] = ldin(src, i - off, bf);
}

__global__ void k_fixup(u16* __restrict__ WfrB, float* __restrict__ wdxd,
                        const void* __restrict__ Wdx, const int* __restrict__ flagp) {
    int f = threadIdx.x;  // 256
    int bf = *flagp;
    WfrB[f * 256 + f] = 0;
    wdxd[f] = ldin(Wdx, f * 257, bf);
}

// ---- precompute kernels ----
__global__ void k_pack(const void* __restrict__ deltas, const void* __restrict__ mask,
                       const int* __restrict__ flagp,
                       const float* __restrict__ wdxd, const float* __restrict__ bdx,
                       u16* __restrict__ dbf_all, u16* __restrict__ A2_all) {
    int bf = *flagp;
    for (int idx = blockIdx.x * 256 + threadIdx.x; idx < 8388608; idx += gridDim.x * 256) {
        int f = idx & 255;
        int bt = idx >> 8;
        int b = bt >> 6, t = bt & 63;
        float d = ldin(deltas, idx, bf);
        float m = ldin(mask, idx, bf);
        int r = t * 512 + b;
        dbf_all[(r << 8) + f] = f2bf(d);
        float gx = expf(-fmaxf(d * wdxd[f] + bdx[f], 0.f));
        A2_all[(r << 9) + f] = f2bf(gx);
        A2_all[(r << 9) + 256 + f] = f2bf(m);
    }
}

__global__ __launch_bounds__(256) void k_gammaH(const u16* __restrict__ dbf_all,
                                                const u16* __restrict__ WdhB,
                                                const float* __restrict__ bdh,
                                                u16* __restrict__ gammaH) {
    __shared__ u16 lA[2048], lB[2048];
    int m0 = blockIdx.x << 6, n0 = blockIdx.y << 6;
    f32x4 acc[2][2]; ZACC(acc);
    gemm_loop(dbf_all, 256, WdhB, 256, 256, m0, n0, lA, lB, acc);
    int lane = threadIdx.x & 63, wid = threadIdx.x >> 6;
    int wr = wid >> 1, wc = wid & 1;
    int rq = (lane >> 4) << 2, cc = lane & 15;
#pragma unroll
    for (int i = 0; i < 2; i++)
#pragma unroll
        for (int j = 0; j < 2; j++)
#pragma unroll
            for (int q = 0; q < 4; q++) {
                int gr = m0 + (wr << 5) + (i << 4) + rq + q;
                int gc = n0 + (wc << 5) + (j << 4) + cc;
                gammaH[((size_t)gr << 10) + gc] = f2bf(expf(-fmaxf(acc[i][j][q] + bdh[gc], 0.f)));
            }
}

__global__ __launch_bounds__(256) void k_beta(const u16* __restrict__ A2_all,
                                              const u16* __restrict__ WwcB,
                                              const float* __restrict__ bwc,
                                              float* __restrict__ beta_all) {
    __shared__ u16 lA[2048], lB[2048];
    int m0 = blockIdx.x << 6, n0 = blockIdx.y << 6;
    f32x4 acc[2][2]; ZACC(acc);
    gemm_loop(A2_all, 512, WwcB, 512, 512, m0, n0, lA, lB, acc);
    int lane = threadIdx.x & 63, wid = threadIdx.x >> 6;
    int wr = wid >> 1, wc = wid & 1;
    int rq = (lane >> 4) << 2, cc = lane & 15;
#pragma unroll
    for (int i = 0; i < 2; i++)
#pragma unroll
        for (int j = 0; j < 2; j++)
#pragma unroll
            for (int q = 0; q < 4; q++) {
                int gr = m0 + (wr << 5) + (i << 4) + rq + q;
                int gc = n0 + (wc << 5) + (j << 4) + cc;
                beta_all[((size_t)gr << 8) + gc] = acc[i][j][q] + bwc[gc];
            }
}

__global__ void k_hinit(const void* __restrict__ h0, const int* __restrict__ flagp,
                        const u16* __restrict__ gammaH,
                        float* __restrict__ h, u16* __restrict__ hbf) {
    int bf = *flagp;
    int i = blockIdx.x * 256 + threadIdx.x;  // 524288
    float g = bf2f(gammaH[i]);
    float hv = ldin(h0, i, bf) * g;
    h[i] = hv;
    hbf[i] = f2bf(hv);
}

// ---- per-step kernel 1: hist GEMM + feature-regression + combine (16-row stripes) ----
__global__ __launch_bounds__(256) void k_histcomb(
    const u16* __restrict__ hbf, const u16* __restrict__ WhB, const float* __restrict__ bh,
    const u16* __restrict__ WfrB, const float* __restrict__ bfr,
    const float* __restrict__ beta_all,
    const void* __restrict__ x, const void* __restrict__ mask,
    int t, const int* __restrict__ flagp,
    void* __restrict__ out, u16* __restrict__ A3,
    float* __restrict__ lossN, float* __restrict__ lossD) {
    __shared__ u16 lH[16 * 1032];   // padded stride -> 2-way banks on b128 reads
    __shared__ u16 lXR[16 * 264];
    __shared__ float redN[4], redD[4];
    int tid = threadIdx.x;
    int m0 = blockIdx.x << 4;
    int lane = tid & 63, w = tid >> 6;
    int lrow = lane & 15, lseg = lane >> 4;
    int c0 = w << 6;
    int bf = *flagp;

    // stage the block's 16x1024 hbf stripe once
    {
        int row = tid >> 4;
        int kb = (tid & 15) << 3;
        const u16* src = hbf + ((m0 + row) << 10);
#pragma unroll
        for (int j = 0; j < 8; ++j) {
            int k = kb + (j << 7);
            *(uint4*)&lH[row * 1032 + k] = *(const uint4*)&src[k];
        }
    }
    __syncthreads();

    // hist: A from LDS, B (Wh) direct global->reg, no barriers in loop
    f32x4 acc[4] = {};
#pragma unroll 4
    for (int k0 = 0; k0 < 1024; k0 += 32) {
        int kk = k0 + (lseg << 3);
        s16x8 a = *(const s16x8*)&lH[lrow * 1032 + kk];
#pragma unroll
        for (int j = 0; j < 4; ++j) {
            s16x8 b = *(const s16x8*)&WhB[((c0 + (j << 4) + lrow) << 10) + kk];
            acc[j] = __builtin_amdgcn_mfma_f32_16x16x32_bf16(a, b, acc[j], 0, 0, 0);
        }
    }

    // epilogue 1: keep xh/mask/x in regs (same fragment layout reused below), xr -> LDS
    float xhr[4][4], mvr[4][4], xvr[4][4];
#pragma unroll
    for (int j = 0; j < 4; ++j) {
        int gc = c0 + (j << 4) + lrow;
        float bhc = bh[gc];
#pragma unroll
        for (int q = 0; q < 4; ++q) {
            int row = (lseg << 2) + q;
            float v = acc[j][q] + bhc;
            int gidx = ((m0 + row) << 14) + (t << 8) + gc;
            float mv = ldin(mask, gidx, bf);
            float xv = ldin(x, gidx, bf);
            xhr[j][q] = v; mvr[j][q] = mv; xvr[j][q] = xv;
            lXR[row * 264 + gc] = f2bf(mv * xv + (1.f - mv) * v);
        }
    }
    __syncthreads();

    // feature regression: A (xr) from LDS, B (Wfr, diag zeroed) direct global->reg
    f32x4 accF[4] = {};
#pragma unroll
    for (int k0 = 0; k0 < 256; k0 += 32) {
        int kk = k0 + (lseg << 3);
        s16x8 a = *(const s16x8*)&lXR[lrow * 264 + kk];
#pragma unroll
        for (int j = 0; j < 4; ++j) {
            s16x8 b = *(const s16x8*)&WfrB[((c0 + (j << 4) + lrow) << 8) + kk];
            accF[j] = __builtin_amdgcn_mfma_f32_16x16x32_bf16(a, b, accF[j], 0, 0, 0);
        }
    }

    // epilogue 2: combine, loss, outputs, rnn_in pack
    float ln = 0.f, ld = 0.f;
#pragma unroll
    for (int j = 0; j < 4; ++j) {
        int gc = c0 + (j << 4) + lrow;
        float bfrc = bfr[gc];
#pragma unroll
        for (int q = 0; q < 4; ++q) {
            int row = (lseg << 2) + q;
            int gr = m0 + row;
            float xu = accF[j][q] + bfrc;
            float beta = beta_all[((t * 512 + gr) << 8) + gc];
            float xc = beta * xu + (1.f - beta) * xhr[j][q];
            int gidx = (gr << 14) + (t << 8) + gc;
            float mv = mvr[j][q], xv = xvr[j][q];
            stout(out, OREC + gidx, xc, bf);
            float xi = mv * xv + (1.f - mv) * xc;
            stout(out, gidx, xi, bf);
            A3[(gr << 9) + gc] = f2bf(xi);
            A3[(gr << 9) + 256 + gc] = f2bf(mv);
            ln += fabsf(xc - xv) * mv;
            ld += mv;
        }
    }
    for (int o = 32; o > 0; o >>= 1) { ln += __shfl_down(ln, o); ld += __shfl_down(ld, o); }
    if (lane == 0) { redN[w] = ln; redD[w] = ld; }
    __syncthreads();
    if (tid == 0) {
        atomicAdd(&lossN[t], redN[0] + redN[1] + redN[2] + redN[3]);
        atomicAdd(&lossD[t], redD[0] + redD[1] + redD[2] + redD[3]);
    }
}

// ---- per-step kernel 2: fused gates(gi+gh, 3 gates) + GRU + next-step decay ----
// grid (16,16): 32-row x 64-col tiles over [512 x 1024], ping-pong hbf (race fix)
__global__ __launch_bounds__(256) void k_gates2(
    const u16* __restrict__ A3, const u16* __restrict__ WihB,
    const u16* __restrict__ hbf, const u16* __restrict__ WhhB,
    const float* __restrict__ bih, const float* __restrict__ bhh,
    const u16* __restrict__ gammaH, int t,
    float* __restrict__ h, u16* __restrict__ hbf_out) {
    __shared__ u16 lA[32 * 40];      // pad-40: 2-way banks only
    __shared__ u16 lB[3 * 64 * 40];
    int tid = threadIdx.x;
    int m0 = blockIdx.x << 5, n0 = blockIdx.y << 6;
    int lane = tid & 63, w = tid >> 6;
    int wr = w >> 1, wc = w & 1;
    int lrow = lane & 15, lseg = lane >> 4;

    f32x4 aR[2] = {}, aZ[2] = {}, aN1[2] = {}, aN2[2] = {};

    int ar = tid >> 2, as = (tid & 3) << 3;
    uint4 pa, pb0, pb1, pb2;
    auto issue = [&](int it) {
        const u16* Ap; const u16* Bp; int ld, ko;
        if (it < 16) { Ap = A3; Bp = WihB; ld = 512; ko = it << 5; }
        else { Ap = hbf; Bp = WhhB; ld = 1024; ko = (it - 16) << 5; }
        if (tid < 128) pa = *(const uint4*)&Ap[(m0 + ar) * ld + ko + as];
        pb0 = *(const uint4*)&Bp[(n0 + ar) * ld + ko + as];
        pb1 = *(const uint4*)&Bp[(1024 + n0 + ar) * ld + ko + as];
        pb2 = *(const uint4*)&Bp[(2048 + n0 + ar) * ld + ko + as];
    };

    issue(0);
    for (int it = 0; it < 48; ++it) {
        __syncthreads();
        if (tid < 128) *(uint4*)&lA[ar * 40 + as] = pa;
        *(uint4*)&lB[ar * 40 + as] = pb0;
        *(uint4*)&lB[2560 + ar * 40 + as] = pb1;
        *(uint4*)&lB[5120 + ar * 40 + as] = pb2;
        __syncthreads();
        if (it + 1 < 48) issue(it + 1);   // prefetch hides global latency under MFMA
        s16x8 a = *(const s16x8*)&lA[(wr * 16 + lrow) * 40 + (lseg << 3)];
        bool p1 = (it < 16);
#pragma unroll
        for (int jj = 0; jj < 2; ++jj) {
            int brow = (wc * 32 + jj * 16 + lrow) * 40 + (lseg << 3);
            s16x8 b0 = *(const s16x8*)&lB[brow];
            aR[jj] = __builtin_amdgcn_mfma_f32_16x16x32_bf16(a, b0, aR[jj], 0, 0, 0);
            s16x8 b1 = *(const s16x8*)&lB[2560 + brow];
            aZ[jj] = __builtin_amdgcn_mfma_f32_16x16x32_bf16(a, b1, aZ[jj], 0, 0, 0);
            s16x8 b2 = *(const s16x8*)&lB[5120 + brow];
            if (p1) aN1[jj] = __builtin_amdgcn_mfma_f32_16x16x32_bf16(a, b2, aN1[jj], 0, 0, 0);
            else    aN2[jj] = __builtin_amdgcn_mfma_f32_16x16x32_bf16(a, b2, aN2[jj], 0, 0, 0);
        }
    }

    int last = (t == 63);
#pragma unroll
    for (int jj = 0; jj < 2; ++jj) {
        int gc = n0 + wc * 32 + jj * 16 + lrow;
        float bR = bih[gc] + bhh[gc];
        float bZ = bih[1024 + gc] + bhh[1024 + gc];
        float bNi = bih[2048 + gc];
        float bNh = bhh[2048 + gc];
#pragma unroll
        for (int q = 0; q < 4; ++q) {
            int gr = m0 + wr * 16 + (lseg << 2) + q;
            float r = 1.f / (1.f + expf(-(aR[jj][q] + bR)));
            float z = 1.f / (1.f + expf(-(aZ[jj][q] + bZ)));
            float n = tanhf(aN1[jj][q] + bNi + r * (aN2[jj][q] + bNh));
            int idx = (gr << 10) + gc;
            float hv = (1.f - z) * n + z * h[idx];
            if (!last) hv *= bf2f(gammaH[((t + 1) * 512 + gr) * 1024 + gc]);
            h[idx] = hv;
            hbf_out[idx] = f2bf(hv);
        }
    }
}

// ---- epilogue kernels ----
__global__ void k_hout(const float* __restrict__ h, void* __restrict__ out,
                       const int* __restrict__ flagp) {
    int bf = *flagp;
    int i = (blockIdx.x << 8) + threadIdx.x;
    stout(out, OH + i, h[i], bf);
}

__global__ void k_loss(const float* __restrict__ lossN, const float* __restrict__ lossD,
                       void* __restrict__ out, const int* __restrict__ flagp) {
    int t = threadIdx.x;  // 64
    float v = lossN[t] / (lossD[t] + 1e-12f);
    for (int o = 32; o > 0; o >>= 1) v += __shfl_down(v, o);
    if (t == 0) {
        int bf = *flagp;
        stout(out, OLOSS, v, bf);
        stout(out, OLOSS + 1, 0.f, bf);
    }
}

extern "C" void kernel_launch(void* const* d_in, const int* in_sizes, int n_in,
                              void* d_out, int out_size, void* d_ws, size_t ws_size,
                              hipStream_t stream) {
    (void)in_sizes; (void)n_in; (void)out_size; (void)ws_size;
    const void* x = d_in[0];
    const void* mask = d_in[1];
    const void* deltas = d_in[2];
    const void* h0 = d_in[3];
    const void* Wdh = d_in[4];  const void* bdh = d_in[5];
    const void* Wdx = d_in[6];  const void* bdx = d_in[7];
    const void* Wh = d_in[8];   const void* bh = d_in[9];
    const void* Wfr = d_in[10]; const void* bfr = d_in[11];
    const void* Wwc = d_in[12]; const void* bwc = d_in[13];
    const void* Wih = d_in[14]; const void* bih = d_in[15];
    const void* Whh = d_in[16]; const void* bhh = d_in[17];

    char* cur = (char*)d_ws;
    auto carve = [&](size_t bytes) -> char* {
        char* p = cur; cur += (bytes + 255) & ~(size_t)255; return p;
    };
    int* flag = (int*)carve(sizeof(int));
    float* lossN = (float*)carve(64 * 4);
    float* lossD = (float*)carve(64 * 4);
    float* wdxd = (float*)carve(256 * 4);
    float* biasesF = (float*)carve(8192 * 4);
    u16* WdhB = (u16*)carve(262144 * 2);
    u16* WhB = (u16*)carve(262144 * 2);
    u16* WfrB = (u16*)carve(65536 * 2);
    u16* WwcB = (u16*)carve(131072 * 2);
    u16* WihB = (u16*)carve(1572864 * 2);
    u16* WhhB = (u16*)carve(3145728 * 2);
    float* h = (float*)carve(524288 * 4);
    u16* hbf0 = (u16*)carve(524288 * 2);
    u16* hbf1 = (u16*)carve(524288 * 2);
    u16* A3 = (u16*)carve(262144 * 2);
    u16* dbf_all = (u16*)carve((size_t)8388608 * 2);
    u16* A2_all = (u16*)carve((size_t)16777216 * 2);
    u16* gammaH_all = (u16*)carve((size_t)33554432 * 2);
    float* beta_all = (float*)carve((size_t)8388608 * 4);

    float* bdhF = biasesF;
    float* bdxF = biasesF + 1024;
    float* bhF = biasesF + 1280;
    float* bfrF = biasesF + 1536;
    float* bwcF = biasesF + 1792;
    float* bihF = biasesF + 2048;
    float* bhhF = biasesF + 5120;

    // prologue: dtype detect + weight prep
    k_zero<<<1, 64, 0, stream>>>(flag, lossN, lossD);
    k_detect<<<256, 256, 0, stream>>>((const u32*)mask, flag);
    k_cvt_bf<<<1024, 256, 0, stream>>>(Wdh, WdhB, 262144, flag);
    k_cvt_bf<<<1024, 256, 0, stream>>>(Wh, WhB, 262144, flag);
    k_cvt_bf<<<256, 256, 0, stream>>>(Wfr, WfrB, 65536, flag);
    k_cvt_bf<<<512, 256, 0, stream>>>(Wwc, WwcB, 131072, flag);
    k_cvt_bf<<<2048, 256, 0, stream>>>(Wih, WihB, 1572864, flag);
    k_cvt_bf<<<2048, 256, 0, stream>>>(Whh, WhhB, 3145728, flag);
    k_cvt_biases<<<32, 256, 0, stream>>>(bdh, bdx, bh, bfr, bwc, bih, bhh, biasesF, flag);
    k_fixup<<<1, 256, 0, stream>>>(WfrB, wdxd, Wdx, flag);

    // precompute: gamma_x/mask pack, gamma_h for all t, beta for all t
    k_pack<<<8192, 256, 0, stream>>>(deltas, mask, flag, wdxd, bdxF, dbf_all, A2_all);
    k_gammaH<<<dim3(512, 16), 256, 0, stream>>>(dbf_all, WdhB, bdhF, gammaH_all);
    k_beta<<<dim3(512, 4), 256, 0, stream>>>(A2_all, WwcB, bwcF, beta_all);
    k_hinit<<<2048, 256, 0, stream>>>(h0, flag, gammaH_all, h, hbf0);

    u16* hb[2] = { hbf0, hbf1 };
    for (int t = 0; t < 64; ++t) {
        u16* curb = hb[t & 1];
        u16* nxtb = hb[(t + 1) & 1];
        k_histcomb<<<32, 256, 0, stream>>>(curb, WhB, bhF, WfrB, bfrF, beta_all, x, mask,
                                           t, flag, d_out, A3, lossN, lossD);
        k_gates2<<<dim3(16, 16), 256, 0, stream>>>(A3, WihB, curb, WhhB, bihF, bhhF,
                                                   gammaH_all, t, h, nxtb);
    }
    k_hout<<<2048, 256, 0, stream>>>(h, d_out, flag);
    k_loss<<<1, 64, 0, stream>>>(lossN, lossD, d_out, flag);
}